// Round 1
// baseline (1788.203 us; speedup 1.0000x reference)
//
#include <hip/hip_runtime.h>
#include <stdint.h>

#define HDIM  256
#define SEQ   2048
#define BATCH 64

typedef __fp16 half2_t __attribute__((ext_vector_type(2)));
typedef __fp16 f16x8   __attribute__((ext_vector_type(8)));
typedef float  f32x4   __attribute__((ext_vector_type(4)));

__device__ __forceinline__ uint32_t pack2_f16(float a, float b) {
  half2_t h = __builtin_amdgcn_cvt_pkrtz(a, b);
  return __builtin_bit_cast(uint32_t, h);
}

// ---------------------------------------------------------------------------
// Phase 1 (UNCHANGED, proven): xw = x @ W_ih^T via MFMA 16x16x32 f16.
// ---------------------------------------------------------------------------
#define LDK 264  // padded f16 row stride (264*2 B = 528 B; 528%128 != 0)

__global__ __launch_bounds__(256, 1) void xw_gemm_mfma(
    const float* __restrict__ x, const float* __restrict__ W_ih,
    _Float16* __restrict__ xw) {
  __shared__ _Float16 xsh[64 * LDK];  // 33 KB
  const int tid = threadIdx.x;
  const int wave = tid >> 6;
  const int lane = tid & 63;
  const int nl = lane & 15;  // tile col (n) / tile row (m) for A
  const int q = lane >> 4;   // quad

  // B-frag [k][n] = W_ih[n][k]; lane(nl,q) holds k = 32c+8q+j, n = base+nl.
  f16x8 Bf[4][8];
#pragma unroll
  for (int nt = 0; nt < 4; ++nt) {
    const float* wrow = W_ih + (size_t)(wave * 64 + nt * 16 + nl) * HDIM;
#pragma unroll
    for (int c = 0; c < 8; ++c) {
      const float* p = wrow + c * 32 + q * 8;
      f16x8 f;
#pragma unroll
      for (int j = 0; j < 8; ++j) f[j] = (__fp16)p[j];
      Bf[nt][c] = f;
    }
  }

  const size_t row0 = (size_t)blockIdx.x * 256;
  for (int blk = 0; blk < 4; ++blk) {
    const size_t rbase = row0 + (size_t)blk * 64;
    // coalesced load of 64x256 f32 block
    float4 xr[16];
    const float4* xg = (const float4*)(x + rbase * HDIM);
#pragma unroll
    for (int it = 0; it < 16; ++it) xr[it] = xg[(size_t)it * 256 + tid];
    __syncthreads();  // previous block's LDS reads complete
#pragma unroll
    for (int it = 0; it < 16; ++it) {
      int f = it * 1024 + tid * 4;
      int r = f >> 8, k = f & 255;
      uint2 v = make_uint2(pack2_f16(xr[it].x, xr[it].y),
                           pack2_f16(xr[it].z, xr[it].w));
      *(uint2*)(&xsh[r * LDK + k]) = v;
    }
    __syncthreads();

#pragma unroll
    for (int mt = 0; mt < 4; ++mt) {
      f32x4 acc[4] = {f32x4{0.f, 0.f, 0.f, 0.f}, f32x4{0.f, 0.f, 0.f, 0.f},
                      f32x4{0.f, 0.f, 0.f, 0.f}, f32x4{0.f, 0.f, 0.f, 0.f}};
#pragma unroll
      for (int c = 0; c < 8; ++c) {
        f16x8 A = *(const f16x8*)(&xsh[(mt * 16 + nl) * LDK + c * 32 + q * 8]);
#pragma unroll
        for (int nt = 0; nt < 4; ++nt)
          acc[nt] = __builtin_amdgcn_mfma_f32_16x16x32_f16(A, Bf[nt][c],
                                                           acc[nt], 0, 0, 0);
      }
      // D: row = q*4+r, col = nl (within tile)
#pragma unroll
      for (int nt = 0; nt < 4; ++nt)
#pragma unroll
        for (int r = 0; r < 4; ++r) {
          size_t row = rbase + mt * 16 + q * 4 + r;
          xw[row * HDIM + wave * 64 + nt * 16 + nl] = (_Float16)acc[nt][r];
        }
    }
  }
}

// ---------------------------------------------------------------------------
// Phase 2: serial scan, 1 batch/wg, 64 wgs, 4 waves.
// NEW: matvec via MFMA 16x16x32 f16 with broadcast-A rows.
//   - All 16 A-rows hold the same h slice (LDS same-address broadcast read:
//     addr depends only on (c,q), not nl -> conflict-free, 8x ds_read_b128).
//   - Every D row then equals the matvec; lane (nl,q) consumes tile nt=q,
//     element 0 -> output o = wave*64 + q*16 + nl = tid (addressing unchanged).
//   - xw bias folded into the consumed MFMA C-in slot (accA[q][0] = xq).
//   - K split over two accumulator sets (4-deep MFMA chains).
//   - Unconsumed acc slots persist across steps (bounded growth <= ~3e4,
//     harmless); only the 8 consumed slots are re-initialized per step.
// Replaces 128 fdot2 + 48 DPP ops (~350 cy VALU issue) with 32 MFMA
// (~155 cy issue) per wave per step; K-reduce happens inside the MFMA.
// ---------------------------------------------------------------------------
__global__ __launch_bounds__(256, 1) void rnn_scan_kernel(
    const _Float16* __restrict__ xw, const float* __restrict__ W_hh,
    float* __restrict__ out) {
  __shared__ alignas(16) _Float16 hbuf[2][HDIM];
  const int tid = threadIdx.x;
  const int b = blockIdx.x;
  const int wave = tid >> 6;
  const int lane = tid & 63;
  const int nl = lane & 15;
  const int q = lane >> 4;

  // B-frag [k][n] = W_hh[n][k]; lane(nl,q) holds k = 32c+8q+j, n = base+nl.
  f16x8 Bf[4][8];
#pragma unroll
  for (int nt = 0; nt < 4; ++nt) {
    const float* wrow = W_hh + (size_t)(wave * 64 + nt * 16 + nl) * HDIM;
#pragma unroll
    for (int c = 0; c < 8; ++c) {
      const float* p = wrow + c * 32 + q * 8;
      f16x8 f;
#pragma unroll
      for (int j = 0; j < 8; ++j) f[j] = (__fp16)p[j];
      Bf[nt][c] = f;
    }
  }

  hbuf[0][tid] = (_Float16)0.f;

  const _Float16* xwb = xw + (size_t)b * SEQ * HDIM;
  float* outb = out + (size_t)b * SEQ * HDIM;

  _Float16 xq0 = xwb[tid];
  _Float16 xq1 = xwb[HDIM + tid];
  float last_h = 0.f;

  // Accumulators persist across steps; only element 0 of each is consumed
  // and re-initialized per step. Elements 1..3 integrate the (identical-row)
  // matvec over time: bounded by 2048 * 16 ~ 3e4, no overflow, never read.
  f32x4 accA[4] = {f32x4{0.f, 0.f, 0.f, 0.f}, f32x4{0.f, 0.f, 0.f, 0.f},
                   f32x4{0.f, 0.f, 0.f, 0.f}, f32x4{0.f, 0.f, 0.f, 0.f}};
  f32x4 accB[4] = {f32x4{0.f, 0.f, 0.f, 0.f}, f32x4{0.f, 0.f, 0.f, 0.f},
                   f32x4{0.f, 0.f, 0.f, 0.f}, f32x4{0.f, 0.f, 0.f, 0.f}};

  __syncthreads();

  for (int t = 0; t < SEQ; ++t) {
    int tp = t + 2;
    if (tp > SEQ - 1) tp = SEQ - 1;
    _Float16 xq2 = xwb[(size_t)tp * HDIM + tid];

    const _Float16* hb = hbuf[t & 1];
    // Broadcast A-frags: address depends only on (c, q) -> all nl lanes
    // read the same 16 B (same-address broadcast, conflict-free).
    f16x8 A[8];
#pragma unroll
    for (int c = 0; c < 8; ++c)
      A[c] = *(const f16x8*)(hb + c * 32 + q * 8);

    const float xqf = (float)xq0;
    // Re-init only the consumed C slots; fold xw bias into lane's own slot.
#pragma unroll
    for (int nt = 0; nt < 4; ++nt) {
      accA[nt][0] = (q == nt) ? xqf : 0.f;
      accB[nt][0] = 0.f;
    }

#pragma unroll
    for (int c = 0; c < 4; ++c)
#pragma unroll
      for (int nt = 0; nt < 4; ++nt)
        accA[nt] = __builtin_amdgcn_mfma_f32_16x16x32_f16(A[c], Bf[nt][c],
                                                          accA[nt], 0, 0, 0);
#pragma unroll
    for (int c = 4; c < 8; ++c)
#pragma unroll
      for (int nt = 0; nt < 4; ++nt)
        accB[nt] = __builtin_amdgcn_mfma_f32_16x16x32_f16(A[c], Bf[nt][c],
                                                          accB[nt], 0, 0, 0);

    // Select tile nt == q, element 0 (cndmask chain; q bits are loop-invariant)
    float a01 = (q & 1) ? accA[1][0] : accA[0][0];
    float a23 = (q & 1) ? accA[3][0] : accA[2][0];
    float sA = (q & 2) ? a23 : a01;
    float b01 = (q & 1) ? accB[1][0] : accB[0][0];
    float b23 = (q & 1) ? accB[3][0] : accB[2][0];
    float sB = (q & 2) ? b23 : b01;

    float pre = sA + sB;  // xw bias already folded into accA C-in
    float e = __expf(2.0f * pre);
    float hval = 1.0f - 2.0f * __builtin_amdgcn_rcpf(e + 1.0f);

    outb[(size_t)t * HDIM + tid] = hval;
    hbuf[1 - (t & 1)][tid] = (_Float16)hval;
    last_h = hval;

    xq0 = xq1;
    xq1 = xq2;
    __syncthreads();
  }

  out[(size_t)BATCH * SEQ * HDIM + (size_t)b * HDIM + tid] = last_h;
}

extern "C" void kernel_launch(void* const* d_in, const int* in_sizes, int n_in,
                              void* d_out, int out_size, void* d_ws,
                              size_t ws_size, hipStream_t stream) {
  const float* x = (const float*)d_in[0];     // [64, 2048, 256] fp32
  const float* W_ih = (const float*)d_in[1];  // [256, 256] fp32
  const float* W_hh = (const float*)d_in[2];  // [256, 256] fp32
  float* out = (float*)d_out;                 // [64,2048,256] ++ [1,64,256]
  _Float16* xw = (_Float16*)d_ws;             // 131072*256 f16 = 67 MB

  hipLaunchKernelGGL(xw_gemm_mfma, dim3(512), dim3(256), 0, stream, x, W_ih,
                     xw);
  hipLaunchKernelGGL(rnn_scan_kernel, dim3(BATCH), dim3(256), 0, stream, xw,
                     W_hh, out);
}

// Round 2
// 1103.420 us; speedup vs baseline: 1.6206x; 1.6206x over previous
//
#include <hip/hip_runtime.h>
#include <stdint.h>

#define HDIM  256
#define SEQ   2048
#define BATCH 64

typedef __fp16 half2_t __attribute__((ext_vector_type(2)));
typedef __fp16 f16x8   __attribute__((ext_vector_type(8)));
typedef float  f32x4   __attribute__((ext_vector_type(4)));

__device__ __forceinline__ uint32_t pack2_f16(float a, float b) {
  half2_t h = __builtin_amdgcn_cvt_pkrtz(a, b);
  return __builtin_bit_cast(uint32_t, h);
}

// ---------------------------------------------------------------------------
// Phase 1 (UNCHANGED, proven): xw = x @ W_ih^T via MFMA 16x16x32 f16.
// ---------------------------------------------------------------------------
#define LDK 264  // padded f16 row stride (264*2 B = 528 B; 528%128 != 0)

__global__ __launch_bounds__(256, 1) void xw_gemm_mfma(
    const float* __restrict__ x, const float* __restrict__ W_ih,
    _Float16* __restrict__ xw) {
  __shared__ _Float16 xsh[64 * LDK];  // 33 KB
  const int tid = threadIdx.x;
  const int wave = tid >> 6;
  const int lane = tid & 63;
  const int nl = lane & 15;  // tile col (n) / tile row (m) for A
  const int q = lane >> 4;   // quad

  // B-frag [k][n] = W_ih[n][k]; lane(nl,q) holds k = 32c+8q+j, n = base+nl.
  f16x8 Bf[4][8];
#pragma unroll
  for (int nt = 0; nt < 4; ++nt) {
    const float* wrow = W_ih + (size_t)(wave * 64 + nt * 16 + nl) * HDIM;
#pragma unroll
    for (int c = 0; c < 8; ++c) {
      const float* p = wrow + c * 32 + q * 8;
      f16x8 f;
#pragma unroll
      for (int j = 0; j < 8; ++j) f[j] = (__fp16)p[j];
      Bf[nt][c] = f;
    }
  }

  const size_t row0 = (size_t)blockIdx.x * 256;
  for (int blk = 0; blk < 4; ++blk) {
    const size_t rbase = row0 + (size_t)blk * 64;
    // coalesced load of 64x256 f32 block
    float4 xr[16];
    const float4* xg = (const float4*)(x + rbase * HDIM);
#pragma unroll
    for (int it = 0; it < 16; ++it) xr[it] = xg[(size_t)it * 256 + tid];
    __syncthreads();  // previous block's LDS reads complete
#pragma unroll
    for (int it = 0; it < 16; ++it) {
      int f = it * 1024 + tid * 4;
      int r = f >> 8, k = f & 255;
      uint2 v = make_uint2(pack2_f16(xr[it].x, xr[it].y),
                           pack2_f16(xr[it].z, xr[it].w));
      *(uint2*)(&xsh[r * LDK + k]) = v;
    }
    __syncthreads();

#pragma unroll
    for (int mt = 0; mt < 4; ++mt) {
      f32x4 acc[4] = {f32x4{0.f, 0.f, 0.f, 0.f}, f32x4{0.f, 0.f, 0.f, 0.f},
                      f32x4{0.f, 0.f, 0.f, 0.f}, f32x4{0.f, 0.f, 0.f, 0.f}};
#pragma unroll
      for (int c = 0; c < 8; ++c) {
        f16x8 A = *(const f16x8*)(&xsh[(mt * 16 + nl) * LDK + c * 32 + q * 8]);
#pragma unroll
        for (int nt = 0; nt < 4; ++nt)
          acc[nt] = __builtin_amdgcn_mfma_f32_16x16x32_f16(A, Bf[nt][c],
                                                           acc[nt], 0, 0, 0);
      }
      // D: row = q*4+r, col = nl (within tile)
#pragma unroll
      for (int nt = 0; nt < 4; ++nt)
#pragma unroll
        for (int r = 0; r < 4; ++r) {
          size_t row = rbase + mt * 16 + q * 4 + r;
          xw[row * HDIM + wave * 64 + nt * 16 + nl] = (_Float16)acc[nt][r];
        }
    }
  }
}

// ---------------------------------------------------------------------------
// Phase 2: serial scan, 1 batch/wg, 64 wgs, 8 WAVES (512 threads, 2/SIMD).
// MFMA matvec with broadcast-A rows (round-1 layout, correctness-proven):
//   - Wave w owns outputs [32w, 32w+32) = 2 N-tiles. 16 MFMAs/wave/step.
//   - 2 waves/SIMD fill each other's MFMA dependency stalls (round-1 failure
//     was ~900 cy/step of unfilled stalls at 1 wave/SIMD).
//   - Chains interleaved (A0,A1,B0,B1 round-robin): dependent MFMAs ~20 cy
//     apart within a wave.
//   - All 16 A-rows broadcast the same h slice (same-address LDS read).
//   - Lane(nl,q) consumes tile nt=q&1, elem 0 -> output o = 32w+(q&1)*16+nl;
//     q>=2 lanes compute duplicates, only q<2 write.
//   - xw bias folded into each lane's consumed C-in slot.
//   - Unconsumed acc slots persist across steps (bounded, never read).
// ---------------------------------------------------------------------------
__global__ __launch_bounds__(512, 2) void rnn_scan_kernel(
    const _Float16* __restrict__ xw, const float* __restrict__ W_hh,
    float* __restrict__ out) {
  __shared__ alignas(16) _Float16 hbuf[2][HDIM];
  const int tid = threadIdx.x;
  const int b = blockIdx.x;
  const int wave = tid >> 6;
  const int lane = tid & 63;
  const int nl = lane & 15;
  const int q = lane >> 4;
  const int ntq = q & 1;
  const int o = (wave << 5) + (ntq << 4) + nl;  // this lane's output index

  // B-frag [k][n] = W_hh[n][k] for this wave's 2 tiles;
  // lane(nl,q) holds k = 32c+8q+j, n = 32w + 16nt + nl.
  f16x8 Bf[2][8];
#pragma unroll
  for (int nt = 0; nt < 2; ++nt) {
    const float* wrow = W_hh + (size_t)(wave * 32 + nt * 16 + nl) * HDIM;
#pragma unroll
    for (int c = 0; c < 8; ++c) {
      const float* p = wrow + c * 32 + q * 8;
      f16x8 f;
#pragma unroll
      for (int j = 0; j < 8; ++j) f[j] = (__fp16)p[j];
      Bf[nt][c] = f;
    }
  }

  if (tid < HDIM) hbuf[0][tid] = (_Float16)0.f;

  const _Float16* xwb = xw + (size_t)b * SEQ * HDIM;
  float* outb = out + (size_t)b * SEQ * HDIM;

  _Float16 xq0 = xwb[o];
  _Float16 xq1 = xwb[HDIM + o];
  float last_h = 0.f;

  // Persist accumulators; only elem 0 consumed + re-initialized per step.
  // Elems 1..3 integrate bounded junk (<= ~3e4), never read.
  f32x4 accA[2] = {f32x4{0.f, 0.f, 0.f, 0.f}, f32x4{0.f, 0.f, 0.f, 0.f}};
  f32x4 accB[2] = {f32x4{0.f, 0.f, 0.f, 0.f}, f32x4{0.f, 0.f, 0.f, 0.f}};

  __syncthreads();

  for (int t = 0; t < SEQ; ++t) {
    int tp = t + 2;
    if (tp > SEQ - 1) tp = SEQ - 1;
    _Float16 xq2 = xwb[(size_t)tp * HDIM + o];

    const _Float16* hb = hbuf[t & 1];
    // Broadcast A-frags: address depends only on (c, q) -> conflict-free
    // same-address broadcast, 8x ds_read_b128.
    f16x8 A[8];
#pragma unroll
    for (int c = 0; c < 8; ++c)
      A[c] = *(const f16x8*)(hb + c * 32 + q * 8);

    const float xqf = (float)xq0;
    accA[0][0] = ntq ? 0.f : xqf;
    accA[1][0] = ntq ? xqf : 0.f;
    accB[0][0] = 0.f;
    accB[1][0] = 0.f;

    // Interleave 4 independent chains (A0,A1,B0,B1), each 4 deep.
#pragma unroll
    for (int c = 0; c < 4; ++c) {
      accA[0] = __builtin_amdgcn_mfma_f32_16x16x32_f16(A[c], Bf[0][c],
                                                       accA[0], 0, 0, 0);
      accA[1] = __builtin_amdgcn_mfma_f32_16x16x32_f16(A[c], Bf[1][c],
                                                       accA[1], 0, 0, 0);
      accB[0] = __builtin_amdgcn_mfma_f32_16x16x32_f16(A[c + 4], Bf[0][c + 4],
                                                       accB[0], 0, 0, 0);
      accB[1] = __builtin_amdgcn_mfma_f32_16x16x32_f16(A[c + 4], Bf[1][c + 4],
                                                       accB[1], 0, 0, 0);
    }

    float sA = ntq ? accA[1][0] : accA[0][0];
    float sB = ntq ? accB[1][0] : accB[0][0];

    float pre = sA + sB;  // xw bias folded into accA C-in
    float e = __expf(2.0f * pre);
    float hval = 1.0f - 2.0f * __builtin_amdgcn_rcpf(e + 1.0f);

    if (q < 2) {
      outb[(size_t)t * HDIM + o] = hval;
      hbuf[1 - (t & 1)][o] = (_Float16)hval;
    }
    last_h = hval;

    xq0 = xq1;
    xq1 = xq2;
    __syncthreads();
  }

  if (q < 2) out[(size_t)BATCH * SEQ * HDIM + (size_t)b * HDIM + o] = last_h;
}

extern "C" void kernel_launch(void* const* d_in, const int* in_sizes, int n_in,
                              void* d_out, int out_size, void* d_ws,
                              size_t ws_size, hipStream_t stream) {
  const float* x = (const float*)d_in[0];     // [64, 2048, 256] fp32
  const float* W_ih = (const float*)d_in[1];  // [256, 256] fp32
  const float* W_hh = (const float*)d_in[2];  // [256, 256] fp32
  float* out = (float*)d_out;                 // [64,2048,256] ++ [1,64,256]
  _Float16* xw = (_Float16*)d_ws;             // 131072*256 f16 = 67 MB

  hipLaunchKernelGGL(xw_gemm_mfma, dim3(512), dim3(256), 0, stream, x, W_ih,
                     xw);
  hipLaunchKernelGGL(rnn_scan_kernel, dim3(BATCH), dim3(512), 0, stream, xw,
                     W_hh, out);
}